// Round 10
// baseline (63.041 us; speedup 1.0000x reference)
//
#include <hip/hip_runtime.h>
#include <stdint.h>

#define DIMS 96
#define VEC 4
#define LANES (DIMS / VEC)        // 24 lanes cover one 96-dim row as float4
#define SEGS_PER_BLOCK 8
#define THREADS (LANES * SEGS_PER_BLOCK)  // 192 threads = 3 waves
#define UNROLL 8

// clang native vector type: __builtin_nontemporal_* requires a real vector
// type, not HIP's struct-based float4.
typedef float vfloat4 __attribute__((ext_vector_type(4)));

// Round-10: fuse bounds into the main kernel. The gather loop is at a
// system-side random-line service ceiling (r6/r8 nulls: ILP, occupancy,
// nt-streams). Remaining slack was the separate bounds dispatch + graph gap
// (~6us of 58.5). Here 9 threads/block binary-search the block's segment
// boundaries into LDS (one barrier, r2/r3-proven), then the r8 deep-pipeline
// gather loop runs unchanged. One kernel, one launch.
// NOTE: harness delivers integer inputs as int32.

__global__ __launch_bounds__(THREADS) void seg_mean_concat_kernel(
    const float* __restrict__ emb,        // [N, 96]
    const float* __restrict__ self_feats, // [B, 96]
    const int*   __restrict__ nidx,       // [E] int32
    const int*   __restrict__ seg,        // [E] int32, sorted
    float* __restrict__ out,              // [B, 192]
    int B, int E)
{
    __shared__ int sb[SEGS_PER_BLOCK + 1];

    const int b0  = blockIdx.x * SEGS_PER_BLOCK;
    const int tid = threadIdx.x;

    // 9 threads compute lower_bound(seg, b0 + t); hides under other blocks'
    // gather traffic (r3-proven structure).
    if (tid <= SEGS_PER_BLOCK) {
        const int v = b0 + tid;
        int lo = 0, hi = E;
        while (lo < hi) {
            const int mid = (lo + hi) >> 1;
            if (seg[mid] < v) lo = mid + 1; else hi = mid;
        }
        sb[tid] = lo;
    }
    __syncthreads();

    const int g    = tid / LANES;
    const int lane = tid - g * LANES;
    const int b    = b0 + g;
    if (b >= B) return;

    const int start = sb[g];
    const int end   = sb[g + 1];

    const vfloat4* __restrict__ embv = (const vfloat4*)emb;

    // streamed once; keep out of L2 (nt)
    const vfloat4* sfp = (const vfloat4*)(self_feats + (size_t)b * DIMS + lane * VEC);
    const vfloat4 sf = __builtin_nontemporal_load(sfp);

    vfloat4 a0 = (vfloat4)(0.f);
    vfloat4 a1 = (vfloat4)(0.f);

    const int last = end - 1;
    if (start <= last) {
        int j[UNROLL];
        // prologue: first 8 clamped indices (nt: idx array is streamed once)
#pragma unroll
        for (int k = 0; k < UNROLL; ++k) {
            int ee = start + k;
            ee = ee > last ? last : ee;
            j[k] = __builtin_nontemporal_load(nidx + ee);
        }
        __builtin_amdgcn_sched_group_barrier(0x20 /*VMEM_READ*/, UNROLL, 0);

        for (int e = start; e <= last; e += UNROLL) {
            // issue 8 independent row gathers (cached: emb owns the L2)
            vfloat4 v[UNROLL];
#pragma unroll
            for (int k = 0; k < UNROLL; ++k)
                v[k] = embv[(size_t)j[k] * LANES + lane];
            __builtin_amdgcn_sched_group_barrier(0x20 /*VMEM_READ*/, UNROLL, 0);

            // prefetch next iteration's indices (stay in flight through accum)
            const int en = e + UNROLL;
            if (en <= last) {
#pragma unroll
                for (int k = 0; k < UNROLL; ++k) {
                    int ee = en + k;
                    ee = ee > last ? last : ee;
                    j[k] = __builtin_nontemporal_load(nidx + ee);
                }
                __builtin_amdgcn_sched_group_barrier(0x20 /*VMEM_READ*/, UNROLL, 0);
            }

            // masked accumulate (dual accumulators for VALU ILP)
#pragma unroll
            for (int k = 0; k < UNROLL; k += 2) {
                const float w0 = (e + k     <= last) ? 1.0f : 0.0f;
                const float w1 = (e + k + 1 <= last) ? 1.0f : 0.0f;
                a0 += v[k] * w0;
                a1 += v[k + 1] * w1;
            }
        }
    }

    const int cnt = end - start;
    const float inv = 1.0f / (float)(cnt > 0 ? cnt : 1);
    const vfloat4 mean = (a0 + a1) * inv;
    const vfloat4 diff = sf - mean;

    // output is a pure stream: nt store keeps it out of L2
    float* orow = out + (size_t)b * (2 * DIMS);
    __builtin_nontemporal_store(mean, (vfloat4*)(orow + lane * VEC));
    __builtin_nontemporal_store(diff, (vfloat4*)(orow + DIMS + lane * VEC));
}

extern "C" void kernel_launch(void* const* d_in, const int* in_sizes, int n_in,
                              void* d_out, int out_size, void* d_ws, size_t ws_size,
                              hipStream_t stream) {
    const float* emb        = (const float*)d_in[0];
    const float* self_feats = (const float*)d_in[1];
    const int*   nidx       = (const int*)d_in[2];
    const int*   seg        = (const int*)d_in[3];
    float*       out        = (float*)d_out;

    const int B = in_sizes[1] / DIMS;   // self_feats is [B, 96]
    const int E = in_sizes[2];          // neighbor_idx length

    const int grid = (B + SEGS_PER_BLOCK - 1) / SEGS_PER_BLOCK;
    hipLaunchKernelGGL(seg_mean_concat_kernel, dim3(grid), dim3(THREADS), 0, stream,
                       emb, self_feats, nidx, seg, out, B, E);
}

// Round 11
// 56.520 us; speedup vs baseline: 1.1154x; 1.1154x over previous
//
#include <hip/hip_runtime.h>
#include <stdint.h>
#include <limits.h>

#define DIMS 96
#define VEC 4
#define LANES (DIMS / VEC)        // 24 lanes cover one 96-dim row as float4
#define SEGS_PER_BLOCK 8
#define THREADS (LANES * SEGS_PER_BLOCK)  // 192 threads = 3 waves
#define UNROLL 8

// clang native vector type: __builtin_nontemporal_* requires a real vector
// type, not HIP's struct-based float4.
typedef float vfloat4 __attribute__((ext_vector_type(4)));

// Round-11: fused bounds with a FAST search (r10's regression was the 20-step
// serial binary search; here it's 4 dependent probes):
//  - wave-parallel 64-ary search (ballot+popc) for the block's first boundary
//  - 192-thread coalesced linear scan over the block's ~128-edge span finds
//    the remaining 8 transitions (seg is sorted)
//  - then the r8/r9 deep-pipeline gather loop, unchanged (at its random-line
//    service ceiling: ILP/occupancy/nt nulls in r6/r8).
// NOTE: harness delivers integer inputs as int32.

__global__ __launch_bounds__(THREADS) void seg_mean_concat_kernel(
    const float* __restrict__ emb,        // [N, 96]
    const float* __restrict__ self_feats, // [B, 96]
    const int*   __restrict__ nidx,       // [E] int32
    const int*   __restrict__ seg,        // [E] int32, sorted
    float* __restrict__ out,              // [B, 192]
    int B, int E)
{
    __shared__ int sb[SEGS_PER_BLOCK + 1];
    __shared__ int s_start0;

    const int b0  = blockIdx.x * SEGS_PER_BLOCK;
    const int tid = threadIdx.x;
    const int bhi = b0 + SEGS_PER_BLOCK;   // need lower_bounds for b0..bhi

    if (tid >= 1 && tid <= SEGS_PER_BLOCK) sb[tid] = -1;

    // ---- Phase A: wave-parallel 64-ary lower_bound(seg, b0) (wave 0 only) ----
    if (tid < 64) {
        int lo = 0, hi = E;
        while (hi - lo > 63) {
            const int step = (hi - lo) >> 6;              // >= 1
            const int p    = lo + tid * step;             // p < hi <= E
            const bool pred = seg[p] < b0;
            const unsigned long long m = __ballot(pred);
            const int c = (int)__popcll(m);               // monotone prefix
            if (c == 0) { hi = lo; break; }               // lb == lo
            const int nlo = lo + (c - 1) * step + 1;
            hi = (c < 64) ? (lo + c * step) : hi;
            lo = nlo;
        }
        // final narrow stage: width <= 63
        {
            const int w = hi - lo;
            const bool pred = (tid < w) && (seg[lo + tid] < b0);
            const unsigned long long m = __ballot(pred);
            lo += (int)__popcll(m);
        }
        if (tid == 0) { s_start0 = lo; sb[0] = lo; }
    }
    __syncthreads();

    const int start0 = s_start0;

    // ---- Phase B: cooperative linear scan for transitions ----
    // Thread at global pos p marks lower_bound(t) = p+1 for t in (seg[p], seg[p+1]],
    // with virtual seg[E] = +inf. Expected 1 round (block span ~128 < 192).
    for (int r = 0; ; ++r) {
        const int pos = start0 + r * THREADS + tid;
        if (pos < E) {
            const int cur  = seg[pos];
            const int nxtv = (pos + 1 < E) ? seg[pos + 1] : INT_MAX;
            if (r == 0 && tid == 0) {
                // left edge: t in (b0, min(seg[start0], bhi)] -> lb = start0
                const int th0 = cur < bhi ? cur : bhi;
                for (int t = b0 + 1; t <= th0; ++t) sb[t - b0] = start0;
            }
            int tlo = cur + 1; if (tlo < b0 + 1) tlo = b0 + 1;
            int thi = nxtv < bhi ? nxtv : bhi;
            for (int t = tlo; t <= thi; ++t) sb[t - b0] = pos + 1;
        } else if (r == 0 && tid == 0 && start0 >= E) {
            // block entirely past the last edge
            for (int t = 1; t <= SEGS_PER_BLOCK; ++t) sb[t] = E;
        }
        __syncthreads();
        if (sb[SEGS_PER_BLOCK] != -1) break;   // monotone: last bound fills last
        __syncthreads();
    }

    // ---- Phase C: r8 gather loop, unchanged ----
    const int g    = tid / LANES;
    const int lane = tid - g * LANES;
    const int b    = b0 + g;
    if (b >= B) return;

    const int start = sb[g];
    const int end   = sb[g + 1];

    const vfloat4* __restrict__ embv = (const vfloat4*)emb;

    // streamed once; keep out of L2 (nt)
    const vfloat4* sfp = (const vfloat4*)(self_feats + (size_t)b * DIMS + lane * VEC);
    const vfloat4 sf = __builtin_nontemporal_load(sfp);

    vfloat4 a0 = (vfloat4)(0.f);
    vfloat4 a1 = (vfloat4)(0.f);

    const int last = end - 1;
    if (start <= last) {
        int j[UNROLL];
#pragma unroll
        for (int k = 0; k < UNROLL; ++k) {
            int ee = start + k;
            ee = ee > last ? last : ee;
            j[k] = __builtin_nontemporal_load(nidx + ee);
        }
        __builtin_amdgcn_sched_group_barrier(0x20 /*VMEM_READ*/, UNROLL, 0);

        for (int e = start; e <= last; e += UNROLL) {
            vfloat4 v[UNROLL];
#pragma unroll
            for (int k = 0; k < UNROLL; ++k)
                v[k] = embv[(size_t)j[k] * LANES + lane];
            __builtin_amdgcn_sched_group_barrier(0x20 /*VMEM_READ*/, UNROLL, 0);

            const int en = e + UNROLL;
            if (en <= last) {
#pragma unroll
                for (int k = 0; k < UNROLL; ++k) {
                    int ee = en + k;
                    ee = ee > last ? last : ee;
                    j[k] = __builtin_nontemporal_load(nidx + ee);
                }
                __builtin_amdgcn_sched_group_barrier(0x20 /*VMEM_READ*/, UNROLL, 0);
            }

#pragma unroll
            for (int k = 0; k < UNROLL; k += 2) {
                const float w0 = (e + k     <= last) ? 1.0f : 0.0f;
                const float w1 = (e + k + 1 <= last) ? 1.0f : 0.0f;
                a0 += v[k] * w0;
                a1 += v[k + 1] * w1;
            }
        }
    }

    const int cnt = end - start;
    const float inv = 1.0f / (float)(cnt > 0 ? cnt : 1);
    const vfloat4 mean = (a0 + a1) * inv;
    const vfloat4 diff = sf - mean;

    float* orow = out + (size_t)b * (2 * DIMS);
    __builtin_nontemporal_store(mean, (vfloat4*)(orow + lane * VEC));
    __builtin_nontemporal_store(diff, (vfloat4*)(orow + DIMS + lane * VEC));
}

extern "C" void kernel_launch(void* const* d_in, const int* in_sizes, int n_in,
                              void* d_out, int out_size, void* d_ws, size_t ws_size,
                              hipStream_t stream) {
    const float* emb        = (const float*)d_in[0];
    const float* self_feats = (const float*)d_in[1];
    const int*   nidx       = (const int*)d_in[2];
    const int*   seg        = (const int*)d_in[3];
    float*       out        = (float*)d_out;

    const int B = in_sizes[1] / DIMS;   // self_feats is [B, 96]
    const int E = in_sizes[2];          // neighbor_idx length

    const int grid = (B + SEGS_PER_BLOCK - 1) / SEGS_PER_BLOCK;
    hipLaunchKernelGGL(seg_mean_concat_kernel, dim3(grid), dim3(THREADS), 0, stream,
                       emb, self_feats, nidx, seg, out, B, E);
}